// Round 1
// baseline (440.450 us; speedup 1.0000x reference)
//
#include <hip/hip_runtime.h>

// Problem constants (from reference setup_inputs): B=32, C=2, H=W=1024.
#define BB 32
#define HW (1024 * 1024)
#define BLOCKS_PER_SAMPLE 64
#define THREADS 256

// Main pass: per sample b, accumulate
//   s_all[b] = sum over pixels of nll
//   s_one[b] = sum over pixels with target==1 of nll
//   c_one[b] = count of pixels with target==1
// nll = max(x0,x1) + log(1 + exp(-|x0-x1|)) - x_target   (C=2 log-softmax NLL)
__global__ __launch_bounds__(THREADS) void iwce_main(
    const float* __restrict__ outputs,   // [B, 2, H, W]
    const int* __restrict__ targets,     // [B, H, W] (int32)
    float* __restrict__ s_all,
    float* __restrict__ s_one,
    unsigned int* __restrict__ c_one) {
    const int b = blockIdx.y;
    const int chunk = blockIdx.x;              // 0..BLOCKS_PER_SAMPLE-1
    const int tid = threadIdx.x;

    const float* __restrict__ x0p = outputs + (size_t)b * 2 * HW;
    const float* __restrict__ x1p = x0p + HW;
    const int* __restrict__ tp = targets + (size_t)b * HW;

    const int pixelsPerBlock = HW / BLOCKS_PER_SAMPLE;   // 16384
    const int base = chunk * pixelsPerBlock;
    const int iters = pixelsPerBlock / (THREADS * 4);    // 16

    float acc_all = 0.f;
    float acc_one = 0.f;
    unsigned int cnt_one = 0u;

#pragma unroll 4
    for (int j = 0; j < iters; ++j) {
        const int idx = base + (j * THREADS + tid) * 4;
        const float4 x0 = *reinterpret_cast<const float4*>(x0p + idx);
        const float4 x1 = *reinterpret_cast<const float4*>(x1p + idx);
        const int4 t = *reinterpret_cast<const int4*>(tp + idx);

        {
            const float a = x0.x, c = x1.x;
            const float m = fmaxf(a, c);
            const float nll = m + __logf(1.0f + __expf(-fabsf(a - c))) - (t.x ? c : a);
            acc_all += nll;
            if (t.x) { acc_one += nll; cnt_one++; }
        }
        {
            const float a = x0.y, c = x1.y;
            const float m = fmaxf(a, c);
            const float nll = m + __logf(1.0f + __expf(-fabsf(a - c))) - (t.y ? c : a);
            acc_all += nll;
            if (t.y) { acc_one += nll; cnt_one++; }
        }
        {
            const float a = x0.z, c = x1.z;
            const float m = fmaxf(a, c);
            const float nll = m + __logf(1.0f + __expf(-fabsf(a - c))) - (t.z ? c : a);
            acc_all += nll;
            if (t.z) { acc_one += nll; cnt_one++; }
        }
        {
            const float a = x0.w, c = x1.w;
            const float m = fmaxf(a, c);
            const float nll = m + __logf(1.0f + __expf(-fabsf(a - c))) - (t.w ? c : a);
            acc_all += nll;
            if (t.w) { acc_one += nll; cnt_one++; }
        }
    }

    // Wave (64-lane) reduction, then cross-wave via LDS, then 3 atomics/block.
    const int lane = tid & 63;
    const int wid = tid >> 6;
#pragma unroll
    for (int off = 32; off; off >>= 1) {
        acc_all += __shfl_down(acc_all, off, 64);
        acc_one += __shfl_down(acc_one, off, 64);
        cnt_one += __shfl_down(cnt_one, off, 64);
    }
    __shared__ float sA[THREADS / 64], sO[THREADS / 64];
    __shared__ unsigned int sC[THREADS / 64];
    if (lane == 0) { sA[wid] = acc_all; sO[wid] = acc_one; sC[wid] = cnt_one; }
    __syncthreads();
    if (tid == 0) {
        float a = 0.f, o = 0.f; unsigned int c = 0u;
#pragma unroll
        for (int w = 0; w < THREADS / 64; ++w) { a += sA[w]; o += sO[w]; c += sC[w]; }
        atomicAdd(&s_all[b], a);
        atomicAdd(&s_one[b], o);
        atomicAdd(&c_one[b], c);
    }
}

// Finalize: per-sample weights + weighted mean ratio, then mean over B.
__global__ __launch_bounds__(64) void iwce_final(
    const float* __restrict__ s_all,
    const float* __restrict__ s_one,
    const unsigned int* __restrict__ c_one,
    float* __restrict__ out) {
    const int lane = threadIdx.x;  // 0..63
    float v = 0.f;
    if (lane < BB) {
        const float sa = s_all[lane];
        const float s1 = s_one[lane];
        const float n1 = (float)c_one[lane];
        const float n0 = (float)HW - n1;
        const float invHW = 1.0f / (float)HW;
        // weights: wraw0 = 1 - n0/HW = n1/HW ; wraw1 = n0/HW ; mean = 0.5
        // smoothed: w = wraw*(1-0.6) + 0.5*0.6 = wraw*0.4 + 0.3
        const float w0 = (n1 * invHW) * 0.4f + 0.3f;
        const float w1 = (n0 * invHW) * 0.4f + 0.3f;
        const float num = w0 * (sa - s1) + w1 * s1;
        const float den = w0 * n0 + w1 * n1;
        v = num / den;
    }
#pragma unroll
    for (int off = 32; off; off >>= 1) v += __shfl_down(v, off, 64);
    if (lane == 0) out[0] = v * (1.0f / (float)BB);
}

extern "C" void kernel_launch(void* const* d_in, const int* in_sizes, int n_in,
                              void* d_out, int out_size, void* d_ws, size_t ws_size,
                              hipStream_t stream) {
    const float* outputs = (const float*)d_in[0];
    const int* targets = (const int*)d_in[1];
    float* out = (float*)d_out;

    // Workspace: s_all[32] | s_one[32] | c_one[32]
    float* s_all = (float*)d_ws;
    float* s_one = s_all + BB;
    unsigned int* c_one = (unsigned int*)(s_one + BB);

    hipMemsetAsync(d_ws, 0, (2 * BB) * sizeof(float) + BB * sizeof(unsigned int), stream);

    iwce_main<<<dim3(BLOCKS_PER_SAMPLE, BB), THREADS, 0, stream>>>(
        outputs, targets, s_all, s_one, c_one);
    iwce_final<<<1, 64, 0, stream>>>(s_all, s_one, c_one, out);
}

// Round 2
// 401.999 us; speedup vs baseline: 1.0956x; 1.0956x over previous
//
#include <hip/hip_runtime.h>

// Problem constants (from reference setup_inputs): B=32, C=2, H=W=1024.
#define BB 32
#define HW (1024 * 1024)
#define BLOCKS_PER_SAMPLE 64
#define NPART (BB * BLOCKS_PER_SAMPLE)   // 2048 partial slots
#define THREADS 256

typedef float v4f __attribute__((ext_vector_type(4)));
typedef int v4i __attribute__((ext_vector_type(4)));

// Main pass: per (sample b, chunk): accumulate over 16384 pixels
//   pA[g] = sum nll ; pO[g] = sum nll where t==1 ; pC[g] = count t==1
// nll = max(x0,x1) + log(1 + exp(-|x0-x1|)) - x_target   (C=2 log-softmax NLL)
// No atomics, no memset: every partial slot is written exactly once per call.
__global__ __launch_bounds__(THREADS) void iwce_main(
    const float* __restrict__ outputs,   // [B, 2, H, W]
    const int* __restrict__ targets,     // [B, H, W] (int32, values 0/1)
    float* __restrict__ pA,
    float* __restrict__ pO,
    float* __restrict__ pC) {
    const int b = blockIdx.y;
    const int chunk = blockIdx.x;              // 0..BLOCKS_PER_SAMPLE-1
    const int tid = threadIdx.x;
    const int g = b * BLOCKS_PER_SAMPLE + chunk;

    const float* __restrict__ x0p = outputs + (size_t)b * 2 * HW;
    const float* __restrict__ x1p = x0p + HW;
    const int* __restrict__ tp = targets + (size_t)b * HW;

    const int pixelsPerBlock = HW / BLOCKS_PER_SAMPLE;   // 16384
    const int base = chunk * pixelsPerBlock;
    const int iters = pixelsPerBlock / (THREADS * 4);    // 16

    float acc_all = 0.f;
    float acc_one = 0.f;
    int cnt_one = 0;

#pragma unroll 4
    for (int j = 0; j < iters; ++j) {
        const int idx = base + (j * THREADS + tid) * 4;
        const v4f x0 = __builtin_nontemporal_load(reinterpret_cast<const v4f*>(x0p + idx));
        const v4f x1 = __builtin_nontemporal_load(reinterpret_cast<const v4f*>(x1p + idx));
        const v4i t = __builtin_nontemporal_load(reinterpret_cast<const v4i*>(tp + idx));

#pragma unroll
        for (int k = 0; k < 4; ++k) {
            const float a = x0[k], c = x1[k];
            const float m = fmaxf(a, c);
            const float nll = m + __logf(1.0f + __expf(-fabsf(a - c))) - (t[k] ? c : a);
            acc_all += nll;
            acc_one += t[k] ? nll : 0.0f;   // branch-free select
            cnt_one += t[k];                // targets are 0/1
        }
    }

    // Wave (64-lane) reduction, then cross-wave via LDS; one store per block.
    const int lane = tid & 63;
    const int wid = tid >> 6;
    float acc_cnt = (float)cnt_one;
#pragma unroll
    for (int off = 32; off; off >>= 1) {
        acc_all += __shfl_down(acc_all, off, 64);
        acc_one += __shfl_down(acc_one, off, 64);
        acc_cnt += __shfl_down(acc_cnt, off, 64);
    }
    __shared__ float sA[THREADS / 64], sO[THREADS / 64], sC[THREADS / 64];
    if (lane == 0) { sA[wid] = acc_all; sO[wid] = acc_one; sC[wid] = acc_cnt; }
    __syncthreads();
    if (tid == 0) {
        float a = 0.f, o = 0.f, c = 0.f;
#pragma unroll
        for (int w = 0; w < THREADS / 64; ++w) { a += sA[w]; o += sO[w]; c += sC[w]; }
        pA[g] = a; pO[g] = o; pC[g] = c;
    }
}

// Finalize: reduce 64 partials per sample (one wave per sample, two passes),
// compute per-sample weighted ratio, then mean over B. One block.
__global__ __launch_bounds__(1024) void iwce_final(
    const float* __restrict__ pA,
    const float* __restrict__ pO,
    const float* __restrict__ pC,
    float* __restrict__ out) {
    const int tid = threadIdx.x;      // 0..1023 (16 waves)
    const int wave = tid >> 6;
    const int lane = tid & 63;
    __shared__ float sv[BB];

#pragma unroll
    for (int s = 0; s < 2; ++s) {
        const int b = wave + s * 16;                 // sample index
        const int idx = b * BLOCKS_PER_SAMPLE + lane;
        float a = pA[idx], o = pO[idx], c = pC[idx];
#pragma unroll
        for (int off = 32; off; off >>= 1) {
            a += __shfl_down(a, off, 64);
            o += __shfl_down(o, off, 64);
            c += __shfl_down(c, off, 64);
        }
        if (lane == 0) {
            const float n1 = c;
            const float n0 = (float)HW - n1;
            const float invHW = 1.0f / (float)HW;
            // raw weights: w0 = n1/HW, w1 = n0/HW (1 - freq); mean = 0.5
            // smoothed: w = raw*0.4 + 0.3
            const float w0 = (n1 * invHW) * 0.4f + 0.3f;
            const float w1 = (n0 * invHW) * 0.4f + 0.3f;
            const float num = w0 * (a - o) + w1 * o;
            const float den = w0 * n0 + w1 * n1;
            sv[b] = num / den;
        }
    }
    __syncthreads();
    if (tid == 0) {
        float s = 0.f;
#pragma unroll
        for (int b = 0; b < BB; ++b) s += sv[b];
        out[0] = s * (1.0f / (float)BB);
    }
}

extern "C" void kernel_launch(void* const* d_in, const int* in_sizes, int n_in,
                              void* d_out, int out_size, void* d_ws, size_t ws_size,
                              hipStream_t stream) {
    const float* outputs = (const float*)d_in[0];
    const int* targets = (const int*)d_in[1];
    float* out = (float*)d_out;

    // Workspace layout: pA[2048] | pO[2048] | pC[2048] (all written every call)
    float* pA = (float*)d_ws;
    float* pO = pA + NPART;
    float* pC = pO + NPART;

    iwce_main<<<dim3(BLOCKS_PER_SAMPLE, BB), THREADS, 0, stream>>>(
        outputs, targets, pA, pO, pC);
    iwce_final<<<1, 1024, 0, stream>>>(pA, pO, pC, out);
}